// Round 1
// baseline (24834.578 us; speedup 1.0000x reference)
//
#include <hip/hip_runtime.h>

typedef short short8 __attribute__((ext_vector_type(8)));
typedef float f32x4 __attribute__((ext_vector_type(4)));

__device__ __forceinline__ unsigned short f2bf(float x) {
    unsigned int u = __float_as_uint(x);
    u += 0x7FFFu + ((u >> 16) & 1u);   // round-to-nearest-even
    return (unsigned short)(u >> 16);
}

__device__ __forceinline__ float sigmoidf_(float x) {
    return 1.0f / (1.0f + __expf(-x));   // saturates correctly at +/-inf
}

__device__ __forceinline__ float tanhf_(float x) {
    float ax = fabsf(x);
    float e = __expf(2.0f * ax);         // inf for large ax -> t = 1 (safe)
    float t = 1.0f - 2.0f / (e + 1.0f);
    return copysignf(t, x);
}

// Generic LSTM-step tile: computes 32 batch rows x 32 hidden units of
//   g = [A1|A2] @ W^T (+ bias + x*Wx), then the cell update.
// W is bf16 [4096, K] row-major (K = 1024 or 2048). A1/A2 are bf16 [256,1024].
// c (fp32) is lane-owned -> updated in place. h written bf16 to hout.
// If fcW != null, also accumulates y[br] += h . fcW (+ fcb once) via atomics.
__device__ void lstm_tile(
    int idx,
    const unsigned short* __restrict__ A1,
    const unsigned short* __restrict__ A2,   // nullptr if K==1024
    const unsigned short* __restrict__ W,
    int K,
    const float* __restrict__ bias,          // [4096]
    const float* __restrict__ xvec, int xstride,  // per-row scalar input (or null)
    const float* __restrict__ Wx,            // [4096] input weight col (or null)
    float* __restrict__ c,                   // [256,1024] fp32, in-place
    unsigned short* __restrict__ hout,       // [256,1024] bf16
    const float* __restrict__ fcW,           // [1024] or null
    const float* __restrict__ fcb,           // [1]
    float* __restrict__ yout)                // y[br*96] target (column base)
{
    const int tid  = threadIdx.x;
    const int lane = tid & 63;
    const int wave = tid >> 6;
    const int rg = idx >> 5;                  // 0..7  -> batch group of 32
    const int ug = idx & 31;                  // 0..31 -> unit group of 32
    const int mb = rg * 32 + (wave >> 1) * 16;  // wave: 16 batch rows
    const int ub = ug * 32 + (wave & 1) * 16;   // wave: 16 units (x4 gates)
    const int q = lane >> 4;
    const int m = lane & 15;

    const unsigned short* a1p = A1 + (mb + m) * 1024 + q * 8;
    const unsigned short* a2p = A2 ? (A2 + (mb + m) * 1024 + q * 8) : nullptr;
    const unsigned short* wp  = W + (ub + m) * K + q * 8;
    const int wg = 1024 * K;                  // W row offset per gate

    f32x4 acc0 = {0.f,0.f,0.f,0.f};
    f32x4 acc1 = {0.f,0.f,0.f,0.f};
    f32x4 acc2 = {0.f,0.f,0.f,0.f};
    f32x4 acc3 = {0.f,0.f,0.f,0.f};

    auto ldA = [&](int k) -> short8 {
        const unsigned short* p = (k < 1024) ? (a1p + k) : (a2p + (k - 1024));
        return *(const short8*)p;
    };
    auto ldB = [&](int g, int k) -> short8 {
        return *(const short8*)(wp + g * wg + k);
    };

    // 1-step register prefetch pipeline over K
    short8 a  = ldA(0);
    short8 b0 = ldB(0, 0), b1 = ldB(1, 0), b2 = ldB(2, 0), b3 = ldB(3, 0);
    for (int k = 0; k < K; k += 32) {
        short8 an, bn0, bn1, bn2, bn3;
        const int kn = k + 32;
        if (kn < K) {
            an  = ldA(kn);
            bn0 = ldB(0, kn); bn1 = ldB(1, kn);
            bn2 = ldB(2, kn); bn3 = ldB(3, kn);
        }
        acc0 = __builtin_amdgcn_mfma_f32_16x16x32_bf16(a, b0, acc0, 0, 0, 0);
        acc1 = __builtin_amdgcn_mfma_f32_16x16x32_bf16(a, b1, acc1, 0, 0, 0);
        acc2 = __builtin_amdgcn_mfma_f32_16x16x32_bf16(a, b2, acc2, 0, 0, 0);
        acc3 = __builtin_amdgcn_mfma_f32_16x16x32_bf16(a, b3, acc3, 0, 0, 0);
        a = an; b0 = bn0; b1 = bn1; b2 = bn2; b3 = bn3;
    }

    // Epilogue: lane owns (row = mb + q*4 + r, unit = ub + m) for r in 0..3.
    const int u = ub + m;
    const float biasI = bias[u];
    const float biasF = bias[1024 + u];
    const float biasG = bias[2048 + u];
    const float biasO = bias[3072 + u];
    float wxI = 0.f, wxF = 0.f, wxG = 0.f, wxO = 0.f;
    if (Wx) { wxI = Wx[u]; wxF = Wx[1024 + u]; wxG = Wx[2048 + u]; wxO = Wx[3072 + u]; }

#pragma unroll
    for (int r = 0; r < 4; ++r) {
        const int br = mb + q * 4 + r;
        const float xv = xvec ? xvec[br * xstride] : 0.f;
        const float gi = acc0[r] + biasI + xv * wxI;
        const float gf = acc1[r] + biasF + xv * wxF;
        const float gg = acc2[r] + biasG + xv * wxG;
        const float go = acc3[r] + biasO + xv * wxO;
        const float i = sigmoidf_(gi);
        const float f = sigmoidf_(gf);
        const float o = sigmoidf_(go);
        const float cn = f * c[br * 1024 + u] + i * tanhf_(gg);
        c[br * 1024 + u] = cn;
        const float h = o * tanhf_(cn);
        hout[br * 1024 + u] = f2bf(h);
        if (fcW) {
            float part = h * fcW[u];
            part += __shfl_xor(part, 1);
            part += __shfl_xor(part, 2);
            part += __shfl_xor(part, 4);
            part += __shfl_xor(part, 8);
            if (m == 0) {
                if (ub == 0) part += fcb[0];   // add fc bias exactly once per row
                atomicAdd(&yout[br * 96], part);
            }
        }
    }
}

// Encoder: blocks 0..255 run layer0 step t; blocks 256..511 run layer1 step t-1
// (software pipeline across launches; h0/h1 double-buffered by step parity).
__global__ __launch_bounds__(256) void k_enc_step(
    int t,
    const float* __restrict__ x,         // [256,336]
    const float* __restrict__ Wih0,      // enc_Wih0 [4096]
    const float* __restrict__ b0,
    const unsigned short* __restrict__ Wenc0,   // [4096,1024] bf16
    const unsigned short* __restrict__ Wenc1,   // [4096,2048] bf16 ([Wih1|Whh1])
    const float* __restrict__ b1,
    unsigned short* h0a, unsigned short* h0b,
    unsigned short* h1a, unsigned short* h1b,
    float* c0, float* c1)
{
    unsigned short* h0[2] = {h0a, h0b};
    unsigned short* h1[2] = {h1a, h1b};
    const int blk = blockIdx.x;
    if (blk < 256) {
        if (t >= 336) return;
        lstm_tile(blk, h0[(t + 1) & 1], nullptr, Wenc0, 1024, b0,
                  x + t, 336, Wih0, c0, h0[t & 1],
                  nullptr, nullptr, nullptr);
    } else {
        const int u = t - 1;
        if (u < 0) return;
        lstm_tile(blk - 256, h0[u & 1], h1[(u + 1) & 1], Wenc1, 2048, b1,
                  nullptr, 0, nullptr, c1, h1[u & 1],
                  nullptr, nullptr, nullptr);
    }
}

__global__ __launch_bounds__(256) void k_dec0(
    int s,
    const float* __restrict__ x,
    const float* __restrict__ dout,      // y feedback source
    const float* __restrict__ Wih0,      // dec_Wih0 [4096]
    const float* __restrict__ b0,
    const unsigned short* __restrict__ Wdec0,
    unsigned short* h0a, unsigned short* h0b,
    float* c0)
{
    unsigned short* h0[2] = {h0a, h0b};
    const float* xv;
    int xs;
    if (s == 0) { xv = x + 335; xs = 336; }       // xt = x[:,335,0]
    else        { xv = dout + (s - 1); xs = 96; } // xt = y[s-1]
    lstm_tile(blockIdx.x, h0[(s + 1) & 1], nullptr, Wdec0, 1024, b0,
              xv, xs, Wih0, c0, h0[s & 1],
              nullptr, nullptr, nullptr);
}

__global__ __launch_bounds__(256) void k_dec1(
    int s,
    const unsigned short* __restrict__ Wdec1,   // [4096,2048] ([dWih1|dWhh1])
    const float* __restrict__ b1,
    unsigned short* h0a, unsigned short* h0b,
    unsigned short* h1a, unsigned short* h1b,
    float* c1,
    const float* __restrict__ fcW,
    const float* __restrict__ fcb,
    float* __restrict__ dout)
{
    unsigned short* h0[2] = {h0a, h0b};
    unsigned short* h1[2] = {h1a, h1b};
    lstm_tile(blockIdx.x, h0[s & 1], h1[(s + 1) & 1], Wdec1, 2048, b1,
              nullptr, 0, nullptr, c1, h1[s & 1],
              fcW, fcb, dout + s);
}

// ---- prep: fp32 -> bf16 weight conversion ----
__global__ void k_cast(const float* __restrict__ src, unsigned short* __restrict__ dst, int n4) {
    const int i = blockIdx.x * blockDim.x + threadIdx.x;
    if (i >= n4) return;
    const float4 v = ((const float4*)src)[i];
    ushort4 o;
    o.x = f2bf(v.x); o.y = f2bf(v.y); o.z = f2bf(v.z); o.w = f2bf(v.w);
    ((ushort4*)dst)[i] = o;
}

// dst[j, 0:1024] = a[j, :], dst[j, 1024:2048] = b[j, :]   (bf16)
__global__ void k_cat(const float* __restrict__ a, const float* __restrict__ b,
                      unsigned short* __restrict__ dst, int n4) {
    const int i = blockIdx.x * blockDim.x + threadIdx.x;
    if (i >= n4) return;
    const int j  = i >> 9;          // row (512 x 4 elems per row of 2048)
    const int kq = (i & 511) * 4;
    float4 v;
    if (kq < 1024) v = *(const float4*)(a + j * 1024 + kq);
    else           v = *(const float4*)(b + j * 1024 + (kq - 1024));
    ushort4 o;
    o.x = f2bf(v.x); o.y = f2bf(v.y); o.z = f2bf(v.z); o.w = f2bf(v.w);
    *(ushort4*)(dst + (size_t)j * 2048 + kq) = o;
}

extern "C" void kernel_launch(void* const* d_in, const int* in_sizes, int n_in,
                              void* d_out, int out_size, void* d_ws, size_t ws_size,
                              hipStream_t stream)
{
    const float* x     = (const float*)d_in[0];
    const float* eWih0 = (const float*)d_in[1];
    const float* eWhh0 = (const float*)d_in[2];
    const float* eb0   = (const float*)d_in[3];
    const float* eWih1 = (const float*)d_in[4];
    const float* eWhh1 = (const float*)d_in[5];
    const float* eb1   = (const float*)d_in[6];
    const float* dWih0 = (const float*)d_in[7];
    const float* dWhh0 = (const float*)d_in[8];
    const float* db0   = (const float*)d_in[9];
    const float* dWih1 = (const float*)d_in[10];
    const float* dWhh1 = (const float*)d_in[11];
    const float* db1   = (const float*)d_in[12];
    const float* fcW   = (const float*)d_in[13];
    const float* fcb   = (const float*)d_in[14];
    float* out = (float*)d_out;

    char* ws = (char*)d_ws;
    size_t off = 0;
    auto walloc = [&](size_t bytes) -> void* {
        void* p = ws + off;
        off = (off + bytes + 255) & ~(size_t)255;
        return p;
    };
    unsigned short* Wenc0 = (unsigned short*)walloc((size_t)4096 * 1024 * 2);
    unsigned short* Wenc1 = (unsigned short*)walloc((size_t)4096 * 2048 * 2);
    unsigned short* Wdec0 = (unsigned short*)walloc((size_t)4096 * 1024 * 2);
    unsigned short* Wdec1 = (unsigned short*)walloc((size_t)4096 * 2048 * 2);
    char* stateBase = (char*)walloc((size_t)4 * 524288 + (size_t)2 * 1048576);
    unsigned short* h0a = (unsigned short*)(stateBase);
    unsigned short* h0b = (unsigned short*)(stateBase + 524288);
    unsigned short* h1a = (unsigned short*)(stateBase + 2 * 524288);
    unsigned short* h1b = (unsigned short*)(stateBase + 3 * 524288);
    float* c0 = (float*)(stateBase + 4 * 524288);
    float* c1 = (float*)(stateBase + 4 * 524288 + 1048576);

    // zero states (h=c=0) and output (atomic accumulation target)
    hipMemsetAsync(stateBase, 0, (size_t)4 * 524288 + (size_t)2 * 1048576, stream);
    hipMemsetAsync(d_out, 0, (size_t)out_size * sizeof(float), stream);

    // weight prep (runs every call; ws is re-poisoned by the harness)
    {
        const int n4a = 4096 * 256;   // 4096*1024/4
        const int n4b = 4096 * 512;   // 4096*2048/4
        k_cast<<<n4a / 256, 256, 0, stream>>>(eWhh0, Wenc0, n4a);
        k_cast<<<n4a / 256, 256, 0, stream>>>(dWhh0, Wdec0, n4a);
        k_cat<<<n4b / 256, 256, 0, stream>>>(eWih1, eWhh1, Wenc1, n4b);
        k_cat<<<n4b / 256, 256, 0, stream>>>(dWih1, dWhh1, Wdec1, n4b);
    }

    // encoder: 337 pipelined launches (L0 step t || L1 step t-1)
    for (int t = 0; t <= 336; ++t) {
        k_enc_step<<<512, 256, 0, stream>>>(t, x, eWih0, eb0, Wenc0, Wenc1, eb1,
                                            h0a, h0b, h1a, h1b, c0, c1);
    }

    // decoder: 96 steps x 2 cells (strictly sequential via y feedback)
    for (int s = 0; s < 96; ++s) {
        k_dec0<<<256, 256, 0, stream>>>(s, x, out, dWih0, db0, Wdec0, h0a, h0b, c0);
        k_dec1<<<256, 256, 0, stream>>>(s, Wdec1, db1, h0a, h0b, h1a, h1b, c1,
                                        fcW, fcb, out);
    }
}

// Round 2
// 13871.194 us; speedup vs baseline: 1.7904x; 1.7904x over previous
//
#include <hip/hip_runtime.h>

typedef short short8 __attribute__((ext_vector_type(8)));
typedef float f32x4 __attribute__((ext_vector_type(4)));

#define SMEM_BYTES (2*64*68*4 + 4*64*4)   // two 64x68 f32 tiles + 4x64 fc-reduce

__device__ __forceinline__ unsigned short f2bf(float x) {
    unsigned int u = __float_as_uint(x);
    u += 0x7FFFu + ((u >> 16) & 1u);   // round-to-nearest-even
    return (unsigned short)(u >> 16);
}

__device__ __forceinline__ float sigmoidf_(float x) {
    return 1.0f / (1.0f + __expf(-x));
}

__device__ __forceinline__ float tanhf_(float x) {
    float ax = fabsf(x);
    float e = __expf(2.0f * ax);
    float t = 1.0f - 2.0f / (e + 1.0f);
    return copysignf(t, x);
}

// One LSTM step tile: 64 batch rows x 16 units (x4 gates) of
//   g = [A1|A2] @ W^T (+bias +x*Wx), then cell update.
// Block = 256 threads = 4 waves; waves K-split (KS=K/4 each), 4x4 MFMA
// register blocking, fp32 partial reduction through LDS.
// idx: g = idx>>6 (batch group of 64), ug = idx&63 (unit group of 16).
// NOTE: loads prefetch up to ~208B past the K-slice end -> all A/W buffers
// must have valid memory after them (workspace layout guarantees this).
template<int K>
__device__ __forceinline__ void lstm_tile(
    int idx,
    const unsigned short* __restrict__ A1,   // [256,1024] bf16
    const unsigned short* __restrict__ A2,   // second K-half (K==2048) or null
    const unsigned short* __restrict__ W,    // [4096,K] bf16 row-major
    const float* __restrict__ bias,          // [4096]
    const float* __restrict__ xvec, int xstride,  // per-row scalar input (or null)
    const float* __restrict__ Wx,            // [4096] input weight col (or null)
    float* __restrict__ c,                   // [256,1024] fp32 in-place
    unsigned short* __restrict__ hout,       // [256,1024] bf16
    const float* __restrict__ fcW,           // [1024] or null
    const float* __restrict__ fcb,
    float* __restrict__ yout)                // y column base (stride 96)
{
    extern __shared__ float smem[];
    float* T0  = smem;                 // 64 x 68
    float* T1  = smem + 64 * 68;
    float* red = smem + 2 * 64 * 68;   // 4 x 64

    constexpr int KS = K / 4;
    const int tid  = threadIdx.x;
    const int lane = tid & 63;
    const int wave = tid >> 6;
    const int g  = idx >> 6;
    const int ug = idx & 63;
    const int mb = g * 64;
    const int ub = ug * 16;
    const int q = lane >> 4;
    const int m = lane & 15;

    const int k0 = wave * KS;                         // wave's K-slice start
    const unsigned short* Af = (K == 1024) ? A1 : (wave < 2 ? A1 : A2);
    const int ka = (K == 1024) ? k0 : (k0 & 1023);    // offset within Af
    const unsigned short* ap = Af + (mb + m) * 1024 + ka + q * 8;
    const unsigned short* bp = W + (size_t)(ub + m) * K + k0 + q * 8;
    const ptrdiff_t gstride = (ptrdiff_t)1024 * K;    // W rows per gate

    f32x4 acc[4][4];
#pragma unroll
    for (int i = 0; i < 4; ++i)
#pragma unroll
        for (int j = 0; j < 4; ++j) acc[i][j] = (f32x4){0.f, 0.f, 0.f, 0.f};

    short8 aS[2][4], bS[2][4];
    auto LD = [&](int s, int k) {
#pragma unroll
        for (int mi = 0; mi < 4; ++mi)
            aS[s][mi] = *(const short8*)(ap + mi * (16 * 1024) + k);
#pragma unroll
        for (int gt = 0; gt < 4; ++gt)
            bS[s][gt] = *(const short8*)(bp + gt * gstride + k);
    };
    auto MM = [&](int s) {
#pragma unroll
        for (int mi = 0; mi < 4; ++mi)
#pragma unroll
            for (int gt = 0; gt < 4; ++gt)
                acc[mi][gt] = __builtin_amdgcn_mfma_f32_16x16x32_bf16(
                    aS[s][mi], bS[s][gt], acc[mi][gt], 0, 0, 0);
    };

    LD(0, 0);
    LD(1, 32);
#pragma unroll
    for (int k = 0; k < KS; k += 64) {
        MM(0);
        LD(0, k + 64);   // overruns slice end on last iter: padded/adjacent mem
        MM(1);
        LD(1, k + 96);
    }

    // ---- K-split reduction through LDS ----
    float* Tw = (wave & 1) ? T1 : T0;
    if (wave < 2) {
#pragma unroll
        for (int mi = 0; mi < 4; ++mi)
#pragma unroll
            for (int gt = 0; gt < 4; ++gt)
#pragma unroll
                for (int r = 0; r < 4; ++r)
                    Tw[(mi * 16 + q * 4 + r) * 68 + gt * 16 + m] = acc[mi][gt][r];
    }
    __syncthreads();
    if (wave >= 2) {
#pragma unroll
        for (int mi = 0; mi < 4; ++mi)
#pragma unroll
            for (int gt = 0; gt < 4; ++gt)
#pragma unroll
                for (int r = 0; r < 4; ++r)
                    Tw[(mi * 16 + q * 4 + r) * 68 + gt * 16 + m] += acc[mi][gt][r];
    }
    __syncthreads();

    // ---- epilogue: thread owns (row = tid>>2, units u0..u0+3) ----
    const int lrow = tid >> 2;
    const int uq   = tid & 3;
    const int br   = mb + lrow;
    const int u0   = ub + uq * 4;
    const int toff = lrow * 68 + uq * 4;

    auto gate4 = [&](int gofs) -> float4 {
        float4 a = *(const float4*)(T0 + toff + gofs);
        float4 b = *(const float4*)(T1 + toff + gofs);
        return make_float4(a.x + b.x, a.y + b.y, a.z + b.z, a.w + b.w);
    };
    float4 GI = gate4(0), GF = gate4(16), GG = gate4(32), GO = gate4(48);
    float4 bI = *(const float4*)(bias + u0);
    float4 bF = *(const float4*)(bias + 1024 + u0);
    float4 bG = *(const float4*)(bias + 2048 + u0);
    float4 bO = *(const float4*)(bias + 3072 + u0);
    float4 wI = {0,0,0,0}, wF = {0,0,0,0}, wG = {0,0,0,0}, wO = {0,0,0,0};
    float xv = 0.f;
    if (xvec) {
        xv = xvec[br * xstride];
        wI = *(const float4*)(Wx + u0);
        wF = *(const float4*)(Wx + 1024 + u0);
        wG = *(const float4*)(Wx + 2048 + u0);
        wO = *(const float4*)(Wx + 3072 + u0);
    }
    float4 cc = *(const float4*)(c + (size_t)br * 1024 + u0);

    auto cellc = [&](float gi, float gf, float gg, float go, float cold, float& hO) -> float {
        float i = sigmoidf_(gi);
        float f = sigmoidf_(gf);
        float o = sigmoidf_(go);
        float cn = f * cold + i * tanhf_(gg);
        hO = o * tanhf_(cn);
        return cn;
    };
    float h0v, h1v, h2v, h3v;
    float4 cn;
    cn.x = cellc(GI.x + bI.x + xv * wI.x, GF.x + bF.x + xv * wF.x,
                 GG.x + bG.x + xv * wG.x, GO.x + bO.x + xv * wO.x, cc.x, h0v);
    cn.y = cellc(GI.y + bI.y + xv * wI.y, GF.y + bF.y + xv * wF.y,
                 GG.y + bG.y + xv * wG.y, GO.y + bO.y + xv * wO.y, cc.y, h1v);
    cn.z = cellc(GI.z + bI.z + xv * wI.z, GF.z + bF.z + xv * wF.z,
                 GG.z + bG.z + xv * wG.z, GO.z + bO.z + xv * wO.z, cc.z, h2v);
    cn.w = cellc(GI.w + bI.w + xv * wI.w, GF.w + bF.w + xv * wF.w,
                 GG.w + bG.w + xv * wG.w, GO.w + bO.w + xv * wO.w, cc.w, h3v);
    *(float4*)(c + (size_t)br * 1024 + u0) = cn;
    ushort4 hu;
    hu.x = f2bf(h0v); hu.y = f2bf(h1v); hu.z = f2bf(h2v); hu.w = f2bf(h3v);
    *(ushort4*)(hout + (size_t)br * 1024 + u0) = hu;

    if (fcW) {
        float4 fw = *(const float4*)(fcW + u0);
        float fcp = h0v * fw.x + h1v * fw.y + h2v * fw.z + h3v * fw.w;
        red[uq * 64 + lrow] = fcp;
        __syncthreads();
        if (tid < 64) {
            float s = red[tid] + red[64 + tid] + red[128 + tid] + red[192 + tid];
            if (ub == 0) s += fcb[0];
            atomicAdd(yout + (size_t)(mb + tid) * 96, s);
        }
    }
}

// Encoder: blocks 0..255 layer0 step t; 256..511 layer1 step t-1 (pipelined).
__global__ __launch_bounds__(256, 2) void k_enc_step(
    int t,
    const float* __restrict__ x,
    const float* __restrict__ Wih0, const float* __restrict__ b0,
    const unsigned short* __restrict__ Wenc0,
    const unsigned short* __restrict__ Wenc1, const float* __restrict__ b1,
    unsigned short* h0a, unsigned short* h0b,
    unsigned short* h1a, unsigned short* h1b,
    float* c0, float* c1)
{
    unsigned short* h0[2] = {h0a, h0b};
    unsigned short* h1[2] = {h1a, h1b};
    const int blk = blockIdx.x;
    if (blk < 256) {
        if (t >= 336) return;
        lstm_tile<1024>(blk, h0[(t + 1) & 1], nullptr, Wenc0, b0,
                        x + t, 336, Wih0, c0, h0[t & 1],
                        nullptr, nullptr, nullptr);
    } else {
        const int u = t - 1;
        if (u < 0) return;
        lstm_tile<2048>(blk - 256, h0[u & 1], h1[(u + 1) & 1], Wenc1, b1,
                        nullptr, 0, nullptr, c1, h1[u & 1],
                        nullptr, nullptr, nullptr);
    }
}

__global__ __launch_bounds__(256, 2) void k_dec0(
    int s,
    const float* __restrict__ x,
    const float* __restrict__ dout,
    const float* __restrict__ Wih0, const float* __restrict__ b0,
    const unsigned short* __restrict__ Wdec0,
    unsigned short* h0a, unsigned short* h0b, float* c0)
{
    unsigned short* h0[2] = {h0a, h0b};
    const float* xv; int xs;
    if (s == 0) { xv = x + 335; xs = 336; }
    else        { xv = dout + (s - 1); xs = 96; }
    lstm_tile<1024>(blockIdx.x, h0[(s + 1) & 1], nullptr, Wdec0, b0,
                    xv, xs, Wih0, c0, h0[s & 1],
                    nullptr, nullptr, nullptr);
}

__global__ __launch_bounds__(256, 2) void k_dec1(
    int s,
    const unsigned short* __restrict__ Wdec1, const float* __restrict__ b1,
    unsigned short* h0a, unsigned short* h0b,
    unsigned short* h1a, unsigned short* h1b,
    float* c1,
    const float* __restrict__ fcW, const float* __restrict__ fcb,
    float* __restrict__ dout)
{
    unsigned short* h0[2] = {h0a, h0b};
    unsigned short* h1[2] = {h1a, h1b};
    lstm_tile<2048>(blockIdx.x, h0[s & 1], h1[(s + 1) & 1], Wdec1, b1,
                    nullptr, 0, nullptr, c1, h1[s & 1],
                    fcW, fcb, dout + s);
}

// ---- prep: fp32 -> bf16 weight conversion ----
__global__ void k_cast(const float* __restrict__ src, unsigned short* __restrict__ dst, int n4) {
    const int i = blockIdx.x * blockDim.x + threadIdx.x;
    if (i >= n4) return;
    const float4 v = ((const float4*)src)[i];
    ushort4 o;
    o.x = f2bf(v.x); o.y = f2bf(v.y); o.z = f2bf(v.z); o.w = f2bf(v.w);
    ((ushort4*)dst)[i] = o;
}

__global__ void k_cat(const float* __restrict__ a, const float* __restrict__ b,
                      unsigned short* __restrict__ dst, int n4) {
    const int i = blockIdx.x * blockDim.x + threadIdx.x;
    if (i >= n4) return;
    const int j  = i >> 9;
    const int kq = (i & 511) * 4;
    float4 v;
    if (kq < 1024) v = *(const float4*)(a + j * 1024 + kq);
    else           v = *(const float4*)(b + j * 1024 + (kq - 1024));
    ushort4 o;
    o.x = f2bf(v.x); o.y = f2bf(v.y); o.z = f2bf(v.z); o.w = f2bf(v.w);
    *(ushort4*)(dst + (size_t)j * 2048 + kq) = o;
}

extern "C" void kernel_launch(void* const* d_in, const int* in_sizes, int n_in,
                              void* d_out, int out_size, void* d_ws, size_t ws_size,
                              hipStream_t stream)
{
    const float* x     = (const float*)d_in[0];
    const float* eWih0 = (const float*)d_in[1];
    const float* eWhh0 = (const float*)d_in[2];
    const float* eb0   = (const float*)d_in[3];
    const float* eWih1 = (const float*)d_in[4];
    const float* eWhh1 = (const float*)d_in[5];
    const float* eb1   = (const float*)d_in[6];
    const float* dWih0 = (const float*)d_in[7];
    const float* dWhh0 = (const float*)d_in[8];
    const float* db0   = (const float*)d_in[9];
    const float* dWih1 = (const float*)d_in[10];
    const float* dWhh1 = (const float*)d_in[11];
    const float* db1   = (const float*)d_in[12];
    const float* fcW   = (const float*)d_in[13];
    const float* fcb   = (const float*)d_in[14];
    float* out = (float*)d_out;

    char* ws = (char*)d_ws;
    size_t off = 0;
    auto walloc = [&](size_t bytes) -> void* {
        void* p = ws + off;
        off = (off + bytes + 255) & ~(size_t)255;
        return p;
    };
    unsigned short* Wenc0 = (unsigned short*)walloc((size_t)4096 * 1024 * 2);
    unsigned short* Wenc1 = (unsigned short*)walloc((size_t)4096 * 2048 * 2);
    unsigned short* Wdec0 = (unsigned short*)walloc((size_t)4096 * 1024 * 2);
    unsigned short* Wdec1 = (unsigned short*)walloc((size_t)4096 * 2048 * 2);
    char* stateBase = (char*)walloc((size_t)4 * 524288 + (size_t)2 * 1048576 + 65536);
    unsigned short* h0a = (unsigned short*)(stateBase);
    unsigned short* h0b = (unsigned short*)(stateBase + 524288);
    unsigned short* h1a = (unsigned short*)(stateBase + 2 * 524288);
    unsigned short* h1b = (unsigned short*)(stateBase + 3 * 524288);
    float* c0 = (float*)(stateBase + 4 * 524288);
    float* c1 = (float*)(stateBase + 4 * 524288 + 1048576);
    // trailing 64KB of stateBase alloc = guard for prefetch overruns

    hipMemsetAsync(stateBase, 0, (size_t)4 * 524288 + (size_t)2 * 1048576, stream);
    hipMemsetAsync(d_out, 0, (size_t)out_size * sizeof(float), stream);

    {
        const int n4a = 4096 * 256;
        const int n4b = 4096 * 512;
        k_cast<<<n4a / 256, 256, 0, stream>>>(eWhh0, Wenc0, n4a);
        k_cast<<<n4a / 256, 256, 0, stream>>>(dWhh0, Wdec0, n4a);
        k_cat<<<n4b / 256, 256, 0, stream>>>(eWih1, eWhh1, Wenc1, n4b);
        k_cat<<<n4b / 256, 256, 0, stream>>>(dWih1, dWhh1, Wdec1, n4b);
    }

    for (int t = 0; t <= 336; ++t) {
        k_enc_step<<<512, 256, SMEM_BYTES, stream>>>(t, x, eWih0, eb0, Wenc0, Wenc1, eb1,
                                                     h0a, h0b, h1a, h1b, c0, c1);
    }
    for (int s = 0; s < 96; ++s) {
        k_dec0<<<256, 256, SMEM_BYTES, stream>>>(s, x, out, dWih0, db0, Wdec0, h0a, h0b, c0);
        k_dec1<<<256, 256, SMEM_BYTES, stream>>>(s, Wdec1, db1, h0a, h0b, h1a, h1b, c1,
                                                 fcW, fcb, out);
    }
}

// Round 3
// 10627.931 us; speedup vs baseline: 2.3367x; 1.3052x over previous
//
#include <hip/hip_runtime.h>

typedef short short8 __attribute__((ext_vector_type(8)));
typedef float f32x4 __attribute__((ext_vector_type(4)));

#define SMEM_BYTES (2*64*68*4 + 4*64*4)   // two 64x68 f32 tiles + 4x64 fc-reduce

__device__ __forceinline__ unsigned short f2bf(float x) {
    unsigned int u = __float_as_uint(x);
    u += 0x7FFFu + ((u >> 16) & 1u);   // round-to-nearest-even
    return (unsigned short)(u >> 16);
}

__device__ __forceinline__ float sigmoidf_(float x) {
    return 1.0f / (1.0f + __expf(-x));
}

__device__ __forceinline__ float tanhf_(float x) {
    float ax = fabsf(x);
    float e = __expf(2.0f * ax);
    float t = 1.0f - 2.0f / (e + 1.0f);
    return copysignf(t, x);
}

// ---------------- packed layouts ----------------
// hP  [rg 16][kc 32][lane 64][j 8]  (lane = q*16+m holds h[rg*16+m][kc*32+q*8+j])
// WP  [ug 64][kc K/32][gate 4][lane 64][j 8]
//   (lane holds W[gate*1024+ug*16+m][kc*32+q*8+j])
// Every K-loop load is base + lane*16B  -> one contiguous 1 KB per instruction.

// One LSTM step tile: 64 batch rows x 16 units (x4 gates).
// Block = 4 waves, K-split; 4x4 MFMA register blocking; fp32 LDS reduction.
// Loads prefetch up to 2 chunks (1 KB A / 4 KB W) past the slice end ->
// buffers need guard space after them (workspace layout guarantees this).
template<int K>
__device__ __forceinline__ void lstm_tile(
    int idx,
    const unsigned short* __restrict__ A1,   // hP, first K-half
    const unsigned short* __restrict__ A2,   // hP, second K-half (K==2048) or null
    const unsigned short* __restrict__ W,    // WP packed
    const float* __restrict__ bias,          // [4096]
    const float* __restrict__ xvec, int xstride,
    const float* __restrict__ Wx,            // [4096] or null
    float* __restrict__ c,                   // [256,1024] fp32 in-place
    unsigned short* __restrict__ hout,       // hP packed out
    const float* __restrict__ fcW,
    const float* __restrict__ fcb,
    float* __restrict__ yout)
{
    extern __shared__ float smem[];
    float* T0  = smem;                 // 64 x 68
    float* T1  = smem + 64 * 68;
    float* red = smem + 2 * 64 * 68;   // 4 x 64

    constexpr int KS = K / 4;          // k-span per wave
    constexpr int NC = KS / 32;        // chunks per wave (8 or 16)
    constexpr int KC = K / 32;         // chunks per W row-group
    const int tid  = threadIdx.x;
    const int lane = tid & 63;
    const int wave = tid >> 6;
    const int g  = idx >> 6;           // batch group (64 rows)
    const int ug = idx & 63;           // unit group (16 units)
    const int mb = g * 64;
    const int ub = ug * 16;

    const unsigned short* Af = (K == 1024) ? A1 : (wave < 2 ? A1 : A2);
    const int kcA0 = (wave * NC) & 31;             // chunk offset within Af
    const int kcW0 = wave * NC;
    const unsigned short* ap = Af + ((size_t)(g * 4) * 32 + kcA0) * 512 + lane * 8;
    const unsigned short* bp = W + ((size_t)(ug * KC + kcW0) * 4) * 512 + lane * 8;

    f32x4 acc[4][4];
#pragma unroll
    for (int i = 0; i < 4; ++i)
#pragma unroll
        for (int j = 0; j < 4; ++j) acc[i][j] = (f32x4){0.f, 0.f, 0.f, 0.f};

    short8 aS[2][4], bS[2][4];
    auto LD = [&](int s, int cc) {
#pragma unroll
        for (int mi = 0; mi < 4; ++mi)
            aS[s][mi] = *(const short8*)(ap + mi * 16384 + cc * 512);
#pragma unroll
        for (int gt = 0; gt < 4; ++gt)
            bS[s][gt] = *(const short8*)(bp + (cc * 4 + gt) * 512);
    };
    auto MM = [&](int s) {
#pragma unroll
        for (int mi = 0; mi < 4; ++mi)
#pragma unroll
            for (int gt = 0; gt < 4; ++gt)
                acc[mi][gt] = __builtin_amdgcn_mfma_f32_16x16x32_bf16(
                    aS[s][mi], bS[s][gt], acc[mi][gt], 0, 0, 0);
    };

    LD(0, 0);
    LD(1, 1);
#pragma unroll
    for (int cc = 0; cc < NC; cc += 2) {
        MM(0);
        LD(0, cc + 2);   // last iter overruns slice: guard memory, never consumed
        MM(1);
        LD(1, cc + 3);
    }

    // ---- K-split reduction through LDS ----
    const int q = lane >> 4;
    const int m = lane & 15;
    float* Tw = (wave & 1) ? T1 : T0;
    if (wave < 2) {
#pragma unroll
        for (int mi = 0; mi < 4; ++mi)
#pragma unroll
            for (int gt = 0; gt < 4; ++gt)
#pragma unroll
                for (int r = 0; r < 4; ++r)
                    Tw[(mi * 16 + q * 4 + r) * 68 + gt * 16 + m] = acc[mi][gt][r];
    }
    __syncthreads();
    if (wave >= 2) {
#pragma unroll
        for (int mi = 0; mi < 4; ++mi)
#pragma unroll
            for (int gt = 0; gt < 4; ++gt)
#pragma unroll
                for (int r = 0; r < 4; ++r)
                    Tw[(mi * 16 + q * 4 + r) * 68 + gt * 16 + m] += acc[mi][gt][r];
    }
    __syncthreads();

    // ---- epilogue: thread owns (row = tid>>2, units u0..u0+3) ----
    const int lrow = tid >> 2;
    const int uq   = tid & 3;
    const int br   = mb + lrow;
    const int u0   = ub + uq * 4;
    const int toff = lrow * 68 + uq * 4;

    auto gate4 = [&](int gofs) -> float4 {
        float4 a = *(const float4*)(T0 + toff + gofs);
        float4 b = *(const float4*)(T1 + toff + gofs);
        return make_float4(a.x + b.x, a.y + b.y, a.z + b.z, a.w + b.w);
    };
    float4 GI = gate4(0), GF = gate4(16), GG = gate4(32), GO = gate4(48);
    float4 bI = *(const float4*)(bias + u0);
    float4 bF = *(const float4*)(bias + 1024 + u0);
    float4 bG = *(const float4*)(bias + 2048 + u0);
    float4 bO = *(const float4*)(bias + 3072 + u0);
    float4 wI = {0,0,0,0}, wF = {0,0,0,0}, wG = {0,0,0,0}, wO = {0,0,0,0};
    float xv = 0.f;
    if (xvec) {
        xv = xvec[br * xstride];
        wI = *(const float4*)(Wx + u0);
        wF = *(const float4*)(Wx + 1024 + u0);
        wG = *(const float4*)(Wx + 2048 + u0);
        wO = *(const float4*)(Wx + 3072 + u0);
    }
    float4 cc = *(const float4*)(c + (size_t)br * 1024 + u0);

    auto cellc = [&](float gi, float gf, float gg, float go, float cold, float& hO) -> float {
        float i = sigmoidf_(gi);
        float f = sigmoidf_(gf);
        float o = sigmoidf_(go);
        float cn = f * cold + i * tanhf_(gg);
        hO = o * tanhf_(cn);
        return cn;
    };
    float h0v, h1v, h2v, h3v;
    float4 cn;
    cn.x = cellc(GI.x + bI.x + xv * wI.x, GF.x + bF.x + xv * wF.x,
                 GG.x + bG.x + xv * wG.x, GO.x + bO.x + xv * wO.x, cc.x, h0v);
    cn.y = cellc(GI.y + bI.y + xv * wI.y, GF.y + bF.y + xv * wF.y,
                 GG.y + bG.y + xv * wG.y, GO.y + bO.y + xv * wO.y, cc.y, h1v);
    cn.z = cellc(GI.z + bI.z + xv * wI.z, GF.z + bF.z + xv * wF.z,
                 GG.z + bG.z + xv * wG.z, GO.z + bO.z + xv * wO.z, cc.z, h2v);
    cn.w = cellc(GI.w + bI.w + xv * wI.w, GF.w + bF.w + xv * wF.w,
                 GG.w + bG.w + xv * wG.w, GO.w + bO.w + xv * wO.w, cc.w, h3v);
    *(float4*)(c + (size_t)br * 1024 + u0) = cn;

    // packed h store: hP[rg][kc][q*16+m][j]
    {
        const int rg = br >> 4, ml = br & 15;
        const int kc = u0 >> 5, qq = (u0 >> 3) & 3, jo = u0 & 7;
        ushort4 hu;
        hu.x = f2bf(h0v); hu.y = f2bf(h1v); hu.z = f2bf(h2v); hu.w = f2bf(h3v);
        *(ushort4*)(hout + ((size_t)(rg * 32 + kc) * 64 + qq * 16 + ml) * 8 + jo) = hu;
    }

    if (fcW) {
        float4 fw = *(const float4*)(fcW + u0);
        float fcp = h0v * fw.x + h1v * fw.y + h2v * fw.z + h3v * fw.w;
        red[uq * 64 + lrow] = fcp;
        __syncthreads();
        if (tid < 64) {
            float s = red[tid] + red[64 + tid] + red[128 + tid] + red[192 + tid];
            if (ub == 0) s += fcb[0];
            atomicAdd(yout + (size_t)(mb + tid) * 96, s);
        }
    }
}

// Encoder: blocks 0..255 layer0 step t; 256..511 layer1 step t-1 (pipelined).
__global__ __launch_bounds__(256, 2) void k_enc_step(
    int t,
    const float* __restrict__ x,
    const float* __restrict__ Wih0, const float* __restrict__ b0,
    const unsigned short* __restrict__ Wenc0,
    const unsigned short* __restrict__ Wenc1, const float* __restrict__ b1,
    unsigned short* h0a, unsigned short* h0b,
    unsigned short* h1a, unsigned short* h1b,
    float* c0, float* c1)
{
    unsigned short* h0[2] = {h0a, h0b};
    unsigned short* h1[2] = {h1a, h1b};
    const int blk = blockIdx.x;
    if (blk < 256) {
        if (t >= 336) return;
        lstm_tile<1024>(blk, h0[(t + 1) & 1], nullptr, Wenc0, b0,
                        x + t, 336, Wih0, c0, h0[t & 1],
                        nullptr, nullptr, nullptr);
    } else {
        const int u = t - 1;
        if (u < 0) return;
        lstm_tile<2048>(blk - 256, h0[u & 1], h1[(u + 1) & 1], Wenc1, b1,
                        nullptr, 0, nullptr, c1, h1[u & 1],
                        nullptr, nullptr, nullptr);
    }
}

__global__ __launch_bounds__(256, 2) void k_dec0(
    int s,
    const float* __restrict__ x,
    const float* __restrict__ dout,
    const float* __restrict__ Wih0, const float* __restrict__ b0,
    const unsigned short* __restrict__ Wdec0,
    unsigned short* h0a, unsigned short* h0b, float* c0)
{
    unsigned short* h0[2] = {h0a, h0b};
    const float* xv; int xs;
    if (s == 0) { xv = x + 335; xs = 336; }
    else        { xv = dout + (s - 1); xs = 96; }
    lstm_tile<1024>(blockIdx.x, h0[(s + 1) & 1], nullptr, Wdec0, b0,
                    xv, xs, Wih0, c0, h0[s & 1],
                    nullptr, nullptr, nullptr);
}

__global__ __launch_bounds__(256, 2) void k_dec1(
    int s,
    const unsigned short* __restrict__ Wdec1, const float* __restrict__ b1,
    unsigned short* h0a, unsigned short* h0b,
    unsigned short* h1a, unsigned short* h1b,
    float* c1,
    const float* __restrict__ fcW, const float* __restrict__ fcb,
    float* __restrict__ dout)
{
    unsigned short* h0[2] = {h0a, h0b};
    unsigned short* h1[2] = {h1a, h1b};
    lstm_tile<2048>(blockIdx.x, h0[s & 1], h1[(s + 1) & 1], Wdec1, b1,
                    nullptr, 0, nullptr, c1, h1[s & 1],
                    fcW, fcb, dout + s);
}

// ---- prep: pack fp32 weights into WP fragment order (bf16) ----
// WP[ug][kc][gate][lane][8]; lane=q*16+m holds W[gate*1024+ug*16+m][kc*32+q*8 .. +8]
// For K==2048, source k<1024 -> srcA (Wih1), k>=1024 -> srcB (Whh1), both [4096,1024].
template<int K>
__global__ void k_packW(const float* __restrict__ srcA, const float* __restrict__ srcB,
                        unsigned short* __restrict__ dst)
{
    constexpr int KC = K / 32;
    const int total = 4096 * K / 8;
    const int du = blockIdx.x * blockDim.x + threadIdx.x;
    if (du >= total) return;
    const int lane = du & 63;
    int rest = du >> 6;
    const int gate = rest & 3; rest >>= 2;
    const int kc = rest % KC;
    const int ug = rest / KC;
    const int q = lane >> 4, m = lane & 15;
    const int row = gate * 1024 + ug * 16 + m;
    const int k = kc * 32 + q * 8;
    const float* s;
    if (K == 2048 && k >= 1024) s = srcB + (size_t)row * 1024 + (k - 1024);
    else                        s = srcA + (size_t)row * 1024 + k;
    const float4 v0 = *(const float4*)(s);
    const float4 v1 = *(const float4*)(s + 4);
    short8 o;
    o[0] = (short)f2bf(v0.x); o[1] = (short)f2bf(v0.y);
    o[2] = (short)f2bf(v0.z); o[3] = (short)f2bf(v0.w);
    o[4] = (short)f2bf(v1.x); o[5] = (short)f2bf(v1.y);
    o[6] = (short)f2bf(v1.z); o[7] = (short)f2bf(v1.w);
    *(short8*)(dst + (size_t)du * 8) = o;
}

extern "C" void kernel_launch(void* const* d_in, const int* in_sizes, int n_in,
                              void* d_out, int out_size, void* d_ws, size_t ws_size,
                              hipStream_t stream)
{
    const float* x     = (const float*)d_in[0];
    const float* eWih0 = (const float*)d_in[1];
    const float* eWhh0 = (const float*)d_in[2];
    const float* eb0   = (const float*)d_in[3];
    const float* eWih1 = (const float*)d_in[4];
    const float* eWhh1 = (const float*)d_in[5];
    const float* eb1   = (const float*)d_in[6];
    const float* dWih0 = (const float*)d_in[7];
    const float* dWhh0 = (const float*)d_in[8];
    const float* db0   = (const float*)d_in[9];
    const float* dWih1 = (const float*)d_in[10];
    const float* dWhh1 = (const float*)d_in[11];
    const float* db1   = (const float*)d_in[12];
    const float* fcW   = (const float*)d_in[13];
    const float* fcb   = (const float*)d_in[14];
    float* out = (float*)d_out;

    char* ws = (char*)d_ws;
    size_t off = 0;
    auto walloc = [&](size_t bytes) -> void* {
        void* p = ws + off;
        off = (off + bytes + 255) & ~(size_t)255;
        return p;
    };
    unsigned short* Wenc0 = (unsigned short*)walloc((size_t)4096 * 1024 * 2 + 16384);
    unsigned short* Wenc1 = (unsigned short*)walloc((size_t)4096 * 2048 * 2 + 16384);
    unsigned short* Wdec0 = (unsigned short*)walloc((size_t)4096 * 1024 * 2 + 16384);
    unsigned short* Wdec1 = (unsigned short*)walloc((size_t)4096 * 2048 * 2 + 16384);
    char* stateBase = (char*)walloc((size_t)4 * 524288 + (size_t)2 * 1048576 + 65536);
    unsigned short* h0a = (unsigned short*)(stateBase);
    unsigned short* h0b = (unsigned short*)(stateBase + 524288);
    unsigned short* h1a = (unsigned short*)(stateBase + 2 * 524288);
    unsigned short* h1b = (unsigned short*)(stateBase + 3 * 524288);
    float* c0 = (float*)(stateBase + 4 * 524288);
    float* c1 = (float*)(stateBase + 4 * 524288 + 1048576);
    // trailing 64KB of stateBase alloc = guard for prefetch overruns

    hipMemsetAsync(stateBase, 0, (size_t)4 * 524288 + (size_t)2 * 1048576, stream);
    hipMemsetAsync(d_out, 0, (size_t)out_size * sizeof(float), stream);

    {
        const int n1 = 4096 * 1024 / 8;   // 524288 threads
        const int n2 = 4096 * 2048 / 8;
        k_packW<1024><<<n1 / 256, 256, 0, stream>>>(eWhh0, nullptr, Wenc0);
        k_packW<1024><<<n1 / 256, 256, 0, stream>>>(dWhh0, nullptr, Wdec0);
        k_packW<2048><<<n2 / 256, 256, 0, stream>>>(eWih1, eWhh1, Wenc1);
        k_packW<2048><<<n2 / 256, 256, 0, stream>>>(dWih1, dWhh1, Wdec1);
    }

    for (int t = 0; t <= 336; ++t) {
        k_enc_step<<<512, 256, SMEM_BYTES, stream>>>(t, x, eWih0, eb0, Wenc0, Wenc1, eb1,
                                                     h0a, h0b, h1a, h1b, c0, c1);
    }
    for (int s = 0; s < 96; ++s) {
        k_dec0<<<256, 256, SMEM_BYTES, stream>>>(s, x, out, dWih0, db0, Wdec0, h0a, h0b, c0);
        k_dec1<<<256, 256, SMEM_BYTES, stream>>>(s, Wdec1, db1, h0a, h0b, h1a, h1b, c1,
                                                 fcW, fcb, out);
    }
}